// Round 10
// baseline (84.766 us; speedup 1.0000x reference)
//
#include <hip/hip_runtime.h>
#include <hip/hip_bf16.h>

// NT-Xent (SimCLR) loss, MI355X gfx950.
// loss = (1/N) * sum_i [ ln(S_i - exp2(C1*d_ii)) - (2/C1)*dp_i ]
//   where d = zhat.zhat^T (unit rows), C1 = 2*log2(e),
//   S_i = sum_j exp2(C1*d_ij), dp_i = C1 * d_{i, i^B}.
// zb stores sqrt(C1)*zhat in bf16, pre-swizzled into MFMA fragment order:
// 16B chunk for (tile=row>>4, c, lane=quad*16+t) at uint4 index
//   (tile*4+c)*64 + lane, covering row=tile*16+t, k in [c*32+quad*8, +8).
// R10: R9's phase-2 geometry as a PLAIN kernel (R9 lesson: cooperative
// launch silently fails under the harness's graph capture -- output never
// written). Block covers 256 rows x 256 cols: A loaded ONCE (R5 traffic;
// R8's 128-col blocks doubled A-traffic -> regression) with B staged as two
// sequential 32KB LDS halves -> 4 blocks/CU (R5's 64KB span allowed only 2).
// R4 lesson: watch WRITE_SIZE for scratch-spill; keep VGPR <= 128 (unroll 1).
// R6/R7 lesson: triangular symmetry loses to scheduling overhead at this size.

#define NN 8192
#define BHALF 4096
#define DIMK 128

typedef __bf16 bf16x8 __attribute__((ext_vector_type(8)));
typedef float f32x4 __attribute__((ext_vector_type(4)));

#define C1F 2.8853900817779268f   // 2*log2(e)
#define SCALEF 1.6986436f         // sqrt(C1)

// ---------------- Kernel A: normalize, scale by sqrt(C1), swizzle ----------
__global__ __launch_bounds__(256) void nt_normalize(
    const float* __restrict__ zi, const float* __restrict__ zj,
    unsigned int* __restrict__ zb_packed, float* __restrict__ out) {
  if (blockIdx.x == 0 && threadIdx.x == 0) out[0] = 0.0f;  // runs before finalize
  int row = blockIdx.x * 4 + (threadIdx.x >> 6);
  int lane = threadIdx.x & 63;
  const float* src = (row < BHALF) ? (zi + (size_t)row * DIMK)
                                   : (zj + (size_t)(row - BHALF) * DIMK);
  float2 v = ((const float2*)src)[lane];
  float ss = v.x * v.x + v.y * v.y;
#pragma unroll
  for (int off = 32; off >= 1; off >>= 1) ss += __shfl_xor(ss, off, 64);
  float rn = rsqrtf(ss) * SCALEF;
  __hip_bfloat16 h0 = __float2bfloat16(v.x * rn);
  __hip_bfloat16 h1 = __float2bfloat16(v.y * rn);
  unsigned int packed = ((unsigned int)(*(unsigned short*)&h1) << 16) |
                        (*(unsigned short*)&h0);
  int tile = row >> 4, t = row & 15;
  int cq = lane >> 2;               // chunk index 0..15 (= c*4 + quad)
  int c = cq >> 2, quad = cq & 3;
  size_t widx = ((size_t)((tile * 4 + c) * 64 + quad * 16 + t)) * 4 + (lane & 3);
  zb_packed[widx] = packed;
}

// ---------------- Kernel B: streaming sim + exp2 accumulation --------------
// Grid (32,32) = 1024 blocks; block = 4 waves x 64 rows = 256 rows of strip
// blockIdx.y, sweeping 256 cols (pair blockIdx.x) as two 128-col LDS halves.
// A loaded once per block; 4 blocks/CU.
// C/D: col=lane&15, row=quad*4+reg.
__global__ __launch_bounds__(256, 4) void nt_sim(
    const uint4* __restrict__ zbv, float* __restrict__ part) {
  __shared__ uint4 ldsb[2048];  // 32 KiB: one 128-col half-span

  const int lane = threadIdx.x & 63;
  const int wave = threadIdx.x >> 6;
  const int quad = lane >> 4;
  const int t = lane & 15;
  const int row_tile0 = blockIdx.y * 16 + wave * 4;
  const int cp = blockIdx.x;  // 256-col pair index

  // ---- prefetch first 32KB half while A loads ----
  {
    const char* gsrc = (const char*)zbv + (size_t)(cp * 2 + 0) * 32768;
#pragma unroll
    for (int k = 0; k < 8; ++k) {
      int chunk = k * 4 + wave;
      __builtin_amdgcn_global_load_lds(
          (const __attribute__((address_space(1))) unsigned int*)(
              gsrc + chunk * 1024 + lane * 16),
          (__attribute__((address_space(3))) unsigned int*)(
              (char*)ldsb + chunk * 1024),
          16, 0, 0);
    }
  }

  // ---- A fragments: loaded ONCE for both col-halves (64 VGPRs) ----
  bf16x8 A[4][4];  // [row-tile][K-chunk]
#pragma unroll
  for (int rt = 0; rt < 4; ++rt)
#pragma unroll
    for (int c = 0; c < 4; ++c)
      A[rt][c] = __builtin_bit_cast(
          bf16x8, zbv[(size_t)((row_tile0 + rt) * 4 + c) * 64 + lane]);

  float sum[4][4];
#pragma unroll
  for (int rt = 0; rt < 4; ++rt)
#pragma unroll
    for (int r = 0; r < 4; ++r) sum[rt][r] = 0.f;

#pragma unroll 1
  for (int h = 0; h < 2; ++h) {
    if (h) {
      // refill LDS with second half after all waves finished half 0
      __syncthreads();
      const char* gsrc = (const char*)zbv + (size_t)(cp * 2 + 1) * 32768;
#pragma unroll
      for (int k = 0; k < 8; ++k) {
        int chunk = k * 4 + wave;
        __builtin_amdgcn_global_load_lds(
            (const __attribute__((address_space(1))) unsigned int*)(
                gsrc + chunk * 1024 + lane * 16),
            (__attribute__((address_space(3))) unsigned int*)(
                (char*)ldsb + chunk * 1024),
            16, 0, 0);
      }
    }
    __syncthreads();  // DMA drain + join

    // ---- compute: 8 col-tiles from LDS; unroll 1 keeps VGPR <= 128 ----
#pragma unroll 1
    for (int ct = 0; ct < 8; ++ct) {
      f32x4 acc[4];
#pragma unroll
      for (int rt = 0; rt < 4; ++rt) acc[rt] = (f32x4){0.f, 0.f, 0.f, 0.f};
#pragma unroll
      for (int c = 0; c < 4; ++c) {
        bf16x8 bv = __builtin_bit_cast(bf16x8, ldsb[(ct * 4 + c) * 64 + lane]);
#pragma unroll
        for (int rt = 0; rt < 4; ++rt)
          acc[rt] = __builtin_amdgcn_mfma_f32_16x16x32_bf16(A[rt][c], bv,
                                                            acc[rt], 0, 0, 0);
      }
#pragma unroll
      for (int rt = 0; rt < 4; ++rt)
#pragma unroll
        for (int r = 0; r < 4; ++r)
          sum[rt][r] += __builtin_amdgcn_exp2f(acc[rt][r]);
    }
  }

  // reduce over the 16 col-lanes within each quad
#pragma unroll
  for (int off = 8; off >= 1; off >>= 1)
#pragma unroll
    for (int rt = 0; rt < 4; ++rt)
#pragma unroll
      for (int r = 0; r < 4; ++r)
        sum[rt][r] += __shfl_xor(sum[rt][r], off, 16);

  if (t == 0) {
    float* dst = part + (size_t)cp * NN;
    int row_base = row_tile0 * 16;
#pragma unroll
    for (int rt = 0; rt < 4; ++rt)
#pragma unroll
      for (int r = 0; r < 4; ++r)
        dst[row_base + rt * 16 + quad * 4 + r] = sum[rt][r];
  }
}

// ---------------- Kernel C: finalize ----------------
__device__ __forceinline__ float bf2f(unsigned short s) {
  unsigned int u = (unsigned int)s << 16;
  return __builtin_bit_cast(float, u);
}

__global__ __launch_bounds__(256) void nt_finalize(
    const uint4* __restrict__ zbv, const float* __restrict__ part,
    float* __restrict__ out) {
  int i = blockIdx.x * 256 + threadIdx.x;
  int tile = i >> 4, t = i & 15;
  int p = i ^ BHALF;
  int tilep = p >> 4;
  float S = 0.f;
#pragma unroll 8
  for (int k = 0; k < 32; ++k) S += part[(size_t)k * NN + i];
  float dp = 0.f, dd = 0.f;
#pragma unroll
  for (int cq = 0; cq < 16; ++cq) {
    int c = cq >> 2, q = cq & 3;
    uint4 ua = zbv[(size_t)((tile * 4 + c) * 64 + q * 16 + t)];
    uint4 up = zbv[(size_t)((tilep * 4 + c) * 64 + q * 16 + t)];
    const unsigned short* pa = (const unsigned short*)&ua;
    const unsigned short* pp = (const unsigned short*)&up;
#pragma unroll
    for (int k = 0; k < 8; ++k) {
      float a = bf2f(pa[k]), pv = bf2f(pp[k]);
      dd = fmaf(a, a, dd);
      dp = fmaf(a, pv, dp);
    }
  }
  float diag = __builtin_amdgcn_exp2f(dd);        // exp2(C1 * d_ii)
  float v = logf(S - diag) - (2.0f / C1F) * dp;   // lse_i - pos_i
#pragma unroll
  for (int off = 32; off >= 1; off >>= 1) v += __shfl_xor(v, off, 64);
  __shared__ float wsum[4];
  if ((threadIdx.x & 63) == 0) wsum[threadIdx.x >> 6] = v;
  __syncthreads();
  if (threadIdx.x == 0)
    atomicAdd(out, (wsum[0] + wsum[1] + wsum[2] + wsum[3]) * (1.0f / (float)NN));
}

extern "C" void kernel_launch(void* const* d_in, const int* in_sizes, int n_in,
                              void* d_out, int out_size, void* d_ws,
                              size_t ws_size, hipStream_t stream) {
  const float* zi = (const float*)d_in[0];
  const float* zj = (const float*)d_in[1];

  // ws: zb swizzled bf16 (2 MiB) | part[32][8192] (1 MiB)
  unsigned int* zb = (unsigned int*)d_ws;
  float* part = (float*)((char*)d_ws + (2u << 20));

  nt_normalize<<<NN / 4, 256, 0, stream>>>(zi, zj, zb, (float*)d_out);

  dim3 grid(32, 32);  // 32 col-pairs x 256 cols, 32 row-strips x 256 rows
  nt_sim<<<grid, 256, 0, stream>>>((const uint4*)zb, part);

  nt_finalize<<<NN / 256, 256, 0, stream>>>((const uint4*)zb, part,
                                            (float*)d_out);
}